// Round 12
// baseline (304.958 us; speedup 1.0000x reference)
//
#include <hip/hip_runtime.h>
#include <hip/hip_fp16.h>
#include <hip/hip_fp8.h>

#define N_NODES 50000
#define N_EDGES 800000
#define D_FEAT 64
#define K_HOPS 8
#define OUT_STRIDE ((K_HOPS + 1) * D_FEAT)  // 576
#define NPART 128                 // edge-chunk partitions (1 block/CU @ 100KB LDS)
#define CHUNK (N_EDGES / NPART)   // 6250
#define NWORD (N_NODES / 2)       // 2 nodes per u32 histogram word

#define SCAN_WORDS 512            // words per scan block = 1024 nodes
#define SCAN_NB ((NWORD + SCAN_WORDS - 1) / SCAN_WORDS)  // 49

#define NOCT (N_NODES / 8)        // 6250 octets (8 nodes per wave)

#define DNB 50                    // degree-sort node chunks
#define DCHUNK (N_NODES / DNB)    // 1000 nodes per chunk

// ---------------- ws layout (bytes) ----------------
// No global atomics anywhere; every buffer fully overwritten -> no memset.
// y tables fp8 e4m3 (OCP): 64B row = 1 sector/edge (r11: hops 29->26us,
// absmax 0.054 passes). Residual hop overhead = wave max-degree padding
// (E[max8]~24 vs mean 16 -> 1.75x slots/edge): fixed this round by LPT
// degree-grouped octets via zero-global-atomic LDS counting sort (r7's
// failure modes -- contended global atomics + ascending straggler tail --
// are both designed out).
#define ALIGN256(x) (((x) + 255) & ~(size_t)255)
static const size_t OFF_P     = 0;                                           // u32[128][25000]
static const size_t OFF_BASES = OFF_P + (size_t)NPART * NWORD * 4;           // int[128][N]
static const size_t OFF_OFF   = ALIGN256(OFF_BASES + (size_t)NPART * N_NODES * 4); // int[N+1]
static const size_t OFF_BSUM  = ALIGN256(OFF_OFF   + (size_t)(N_NODES + 1) * 4);   // int[64]
static const size_t OFF_TOTW  = ALIGN256(OFF_BSUM  + 64 * 4);                // u32[NWORD]
static const size_t OFF_DINV  = ALIGN256(OFF_TOTW  + (size_t)NWORD * 4);     // float[N]
static const size_t OFF_CSR   = ALIGN256(OFF_DINV  + (size_t)N_NODES * 4);   // int[E]
static const size_t OFF_DPART = ALIGN256(OFF_CSR   + (size_t)N_EDGES * 4);   // int[50][64]
static const size_t OFF_DBASE = ALIGN256(OFF_DPART + DNB * 64 * 4);          // int[50][64]
static const size_t OFF_PERM  = ALIGN256(OFF_DBASE + DNB * 64 * 4);          // int[N]
static const size_t OFF_XA    = ALIGN256(OFF_PERM  + (size_t)N_NODES * 4);   // fp8[(N+1)*64]
static const size_t OFF_XB    = ALIGN256(OFF_XA + (size_t)(N_NODES + 1) * D_FEAT);

// ---- fp8 e4m3 helpers (hip_fp8.h OCP types; HW cvt on gfx950) ----
__device__ __forceinline__ float2 fp8x2_to_f2(unsigned short s) {
    __hip_fp8x2_e4m3 v;
    v.__x = (__hip_fp8x2_storage_t)s;
    return (float2)v;
}
__device__ __forceinline__ unsigned short f2_to_fp8x2(float a, float b) {
    __hip_fp8x2_e4m3 v(make_float2(a, b));
    return (unsigned short)v.__x;
}
__device__ __forceinline__ unsigned pack_fp8x4(float a, float b, float c, float d) {
    return (unsigned)f2_to_fp8x2(a, b) | ((unsigned)f2_to_fp8x2(c, d) << 16);
}

// ---------------- preprocessing: zero-global-atomic counting sort ----------------
// (identical to r8/r10/r11 -- one-change discipline)

__global__ __launch_bounds__(256, 1) void k_hist(const int* __restrict__ src,
                                                 const int* __restrict__ dst,
                                                 unsigned* __restrict__ p) {
    __shared__ unsigned h[NWORD];  // 100,000 B
    int t = threadIdx.x;
    int base = blockIdx.x * CHUNK;
    for (int w = t; w < NWORD; w += 256) h[w] = 0u;
    __syncthreads();
    for (int j = t; j < CHUNK; j += 256) {
        int s = src[base + j], d = dst[base + j];
        if (s != d) {
            atomicAdd(&h[s >> 1], 1u << (8 * (s & 1)));        // src: bytes 0/1
            atomicAdd(&h[d >> 1], 65536u << (8 * (d & 1)));    // dst: bytes 2/3
        }
    }
    __syncthreads();
    unsigned* o = p + (size_t)blockIdx.x * NWORD;
    for (int w = t; w < NWORD; w += 256) o[w] = h[w];
}

__global__ void k_sum(const unsigned* __restrict__ p, float* __restrict__ dinv,
                      unsigned* __restrict__ totW) {
    int w = blockIdx.x * blockDim.x + threadIdx.x;
    if (w >= NWORD) return;
    unsigned s0 = 0, s1 = 0, s2 = 0, s3 = 0;
    #pragma unroll 4
    for (int c = 0; c < NPART; c += 4) {
        s0 += p[(size_t)(c + 0) * NWORD + w];
        s1 += p[(size_t)(c + 1) * NWORD + w];
        s2 += p[(size_t)(c + 2) * NWORD + w];
        s3 += p[(size_t)(c + 3) * NWORD + w];
    }
    unsigned s = (s0 + s1) + (s2 + s3);
    dinv[2 * w + 0] = rsqrtf((float)((s & 0xffu) + 1u));          // +1 self loop
    dinv[2 * w + 1] = rsqrtf((float)(((s >> 8) & 0xffu) + 1u));
    totW[w] = ((s >> 16) & 0xffu) | ((s >> 24) << 16);            // dst degs packed u16
}

__global__ void k_scan_sums(const unsigned* __restrict__ totW, int* __restrict__ bsum) {
    __shared__ int lds[256];
    int b = blockIdx.x, t = threadIdx.x;
    int wend = min((b + 1) * SCAN_WORDS, NWORD);
    int tot = 0;
    for (int w = b * SCAN_WORDS + t; w < wend; w += 256) {
        unsigned v = totW[w];
        tot += (int)(v & 0xffffu) + (int)(v >> 16);
    }
    lds[t] = tot; __syncthreads();
    for (int str = 128; str > 0; str >>= 1) {
        if (t < str) lds[t] += lds[t + str];
        __syncthreads();
    }
    if (t == 0) bsum[b] = lds[0];
}

__global__ void k_scan_top(int* __restrict__ bsum) {
    int lane = threadIdx.x;  // blockDim = 64
    int orig = (lane < SCAN_NB) ? bsum[lane] : 0;
    int v = orig;
    for (int d = 1; d < 64; d <<= 1) {
        int u = __shfl_up(v, d, 64);
        if (lane >= d) v += u;
    }
    if (lane < SCAN_NB) bsum[lane] = v - orig;  // exclusive
}

__global__ void k_scan_downA(const unsigned* __restrict__ totW, const int* __restrict__ bsum,
                             int* __restrict__ off) {
    __shared__ int lds[256];
    int b = blockIdx.x, t = threadIdx.x;
    int w0 = b * SCAN_WORDS + 2 * t;
    unsigned t0 = (w0 < NWORD) ? totW[w0] : 0u;
    unsigned t1 = (w0 + 1 < NWORD) ? totW[w0 + 1] : 0u;
    int n[4] = { (int)(t0 & 0xffffu), (int)(t0 >> 16),
                 (int)(t1 & 0xffffu), (int)(t1 >> 16) };
    int tsum = (n[0] + n[1]) + (n[2] + n[3]);
    lds[t] = tsum; __syncthreads();
    int x = tsum;
    for (int d = 1; d < 256; d <<= 1) {   // Hillis-Steele inclusive scan
        int u = (t >= d) ? lds[t - d] : 0;
        __syncthreads();
        x += u;
        lds[t] = x;
        __syncthreads();
    }
    int pfx = (x - tsum) + bsum[b];
    #pragma unroll
    for (int j = 0; j < 4; ++j) {
        int node = 2 * w0 + j;
        if (node < N_NODES) {
            off[node] = pfx;
            pfx += n[j];
        } else if (node == N_NODES) {
            off[node] = pfx;
        }
    }
}

__global__ void k_bases(const unsigned* __restrict__ p, const int* __restrict__ off,
                        int* __restrict__ bases) {
    int node = blockIdx.x * blockDim.x + threadIdx.x;
    if (node >= N_NODES) return;
    int w = node >> 1;
    int sh = 16 + 8 * (node & 1);  // dst byte lane
    int acc = off[node];
    for (int c = 0; c < NPART; ++c) {
        bases[(size_t)c * N_NODES + node] = acc;
        acc += (int)((p[(size_t)c * NWORD + w] >> sh) & 0xffu);
    }
}

__global__ __launch_bounds__(256, 1) void k_scatter(const int* __restrict__ src,
                                                    const int* __restrict__ dst,
                                                    const int* __restrict__ bases,
                                                    int* __restrict__ csr) {
    __shared__ unsigned h[NWORD];  // 100,000 B
    int t = threadIdx.x;
    int base = blockIdx.x * CHUNK;
    const int* bp = bases + (size_t)blockIdx.x * N_NODES;
    for (int w = t; w < NWORD; w += 256) h[w] = 0u;
    __syncthreads();
    for (int j = t; j < CHUNK; j += 256) {
        int s = src[base + j], d = dst[base + j];
        if (s == d) continue;
        unsigned old = atomicAdd(&h[d >> 1], (d & 1) ? 65536u : 1u);
        unsigned pw = (d & 1) ? (old >> 16) : (old & 0xffffu);
        csr[bp[d] + (int)pw] = s;
    }
}

// ---------------- LPT degree sort (zero GLOBAL atomics; LDS hists only) ----------------
// bin = 63 - min(deg,63): DESCENDING degree order -> heaviest octets dispatch
// first (LPT; r7's ascending tail straggler designed out). Octets then hold
// ~equal-degree nodes -> wave max-degree padding 1.75x -> ~1.25x.

__global__ void k_dhist(const int* __restrict__ off, int* __restrict__ dpart) {
    __shared__ int h[64];
    int t = threadIdx.x;
    if (t < 64) h[t] = 0;
    __syncthreads();
    int base = blockIdx.x * DCHUNK;
    for (int j = t; j < DCHUNK; j += 256) {
        int deg = off[base + j + 1] - off[base + j];
        atomicAdd(&h[63 - min(deg, 63)], 1);
    }
    __syncthreads();
    if (t < 64) dpart[blockIdx.x * 64 + t] = h[t];
}

__global__ void k_dscan(const int* __restrict__ dpart, int* __restrict__ dbase) {
    __shared__ int colsum[64];
    __shared__ int binstart[64];
    int t = threadIdx.x;  // blockDim = 256; wave 0 does the work
    if (t < 64) {
        int s = 0;
        for (int b = 0; b < DNB; ++b) s += dpart[b * 64 + t];
        colsum[t] = s;
    }
    __syncthreads();
    if (t < 64) {
        int v = colsum[t], x = v;
        for (int d = 1; d < 64; d <<= 1) {
            int u = __shfl_up(x, d, 64);
            if (t >= d) x += u;
        }
        binstart[t] = x - v;  // exclusive over bins
    }
    __syncthreads();
    if (t < 64) {
        int acc = binstart[t];
        for (int b = 0; b < DNB; ++b) {
            dbase[b * 64 + t] = acc;
            acc += dpart[b * 64 + t];
        }
    }
}

__global__ void k_dplace(const int* __restrict__ off, const int* __restrict__ dbase,
                         int* __restrict__ perm) {
    __shared__ int h[64];
    int t = threadIdx.x;
    if (t < 64) h[t] = 0;
    __syncthreads();
    int base = blockIdx.x * DCHUNK;
    const int* db = dbase + blockIdx.x * 64;
    for (int j = t; j < DCHUNK; j += 256) {
        int node = base + j;
        int bin = 63 - min(off[node + 1] - off[node], 63);
        int slot = atomicAdd(&h[bin], 1);
        perm[db[bin] + slot] = node;
    }
}

// ---------------- compute kernels ----------------

// x0: feature -> out col 0 (fp32) and XB = y0 = dinv * x (fp8 e4m3, 64B rows).
// Also zeroes row N (the predication zero-row for hop gathers; fp8 0 = 0x00).
__global__ void k_x0(const float4* __restrict__ feat4, float4* __restrict__ out4,
                     unsigned* __restrict__ y8, const float* __restrict__ dinv) {
    int t = blockIdx.x * blockDim.x + threadIdx.x;  // over (N+1)*16
    if (t >= (N_NODES + 1) * 16) return;
    int row = t >> 4;
    if (row < N_NODES) {
        float4 v = feat4[t];
        out4[(size_t)row * (OUT_STRIDE / 4) + (t & 15)] = v;
        float di = dinv[row];
        y8[t] = pack_fp8x4(v.x * di, v.y * di, v.z * di, v.w * di);
    } else {
        y8[t] = 0u;  // zero row
    }
}

// Octet hop, fp8 rows, LPT-degree-grouped nodes: 8 nodes/wave (via perm),
// 8 lanes/node, 8B per lane -> 64B row -> 1 sector/edge. csr via vector
// load + shuffle broadcast. fp32 accumulate; per-node edge order unchanged
// -> output bit-identical to r11 (absmax 0.05371094).
template <bool WRITE_HALF>
__global__ __launch_bounds__(256) void k_hopf8(
    const uint2* __restrict__ yin,   // (N+1) x 8 x uint2 (64B rows)
    float4* __restrict__ outcol4,    // (float4*)out + k*16; row stride 144
    uint2* __restrict__ yout,
    const int* __restrict__ off, const int* __restrict__ csr,
    const float* __restrict__ dinv, const int* __restrict__ perm) {
    int ow = (blockIdx.x * blockDim.x + threadIdx.x) >> 6;  // octet id
    if (ow >= NOCT) return;
    int lane = threadIdx.x & 63;
    int f = lane & 7;                        // 8B slot: features [8f, 8f+8)
    int node = perm[ow * 8 + (lane >> 3)];   // LPT degree-grouped
    int e0 = off[node], e1 = off[node + 1];
    int deg = e1 - e0;
    float di = dinv[node];
    float a0 = 0.f, a1 = 0.f, a2 = 0.f, a3 = 0.f;
    float a4 = 0.f, a5 = 0.f, a6 = 0.f, a7 = 0.f;
    {
        uint2 sv = yin[(size_t)node * 8 + f];  // self term
        float2 u;
        u = fp8x2_to_f2((unsigned short)(sv.x & 0xffffu)); a0 = u.x; a1 = u.y;
        u = fp8x2_to_f2((unsigned short)(sv.x >> 16));     a2 = u.x; a3 = u.y;
        u = fp8x2_to_f2((unsigned short)(sv.y & 0xffffu)); a4 = u.x; a5 = u.y;
        u = fp8x2_to_f2((unsigned short)(sv.y >> 16));     a6 = u.x; a7 = u.y;
    }

    int nm = deg;  // wave-wide max degree (~deg: octet is degree-homogeneous)
    #pragma unroll
    for (int d = 32; d; d >>= 1) nm = max(nm, __shfl_xor(nm, d, 64));

    int gbase = lane & ~7;  // first lane of this node's 8-lane group

    #define ACC8(q)                                                        \
        {                                                                  \
            float2 u_;                                                     \
            u_ = fp8x2_to_f2((unsigned short)((q).x & 0xffffu));           \
            a0 += u_.x; a1 += u_.y;                                        \
            u_ = fp8x2_to_f2((unsigned short)((q).x >> 16));               \
            a2 += u_.x; a3 += u_.y;                                        \
            u_ = fp8x2_to_f2((unsigned short)((q).y & 0xffffu));           \
            a4 += u_.x; a5 += u_.y;                                        \
            u_ = fp8x2_to_f2((unsigned short)((q).y >> 16));               \
            a6 += u_.x; a7 += u_.y;                                        \
        }

    int cvec = csr[min(e0 + f, N_EDGES - 1)];
    for (int j = 0; j < nm; j += 8) {
        int cnext = csr[min(e0 + j + 8 + f, N_EDGES - 1)];
        int v0 = (j + 0 < deg) ? __shfl(cvec, gbase + 0, 64) : N_NODES;
        int v1 = (j + 1 < deg) ? __shfl(cvec, gbase + 1, 64) : N_NODES;
        int v2 = (j + 2 < deg) ? __shfl(cvec, gbase + 2, 64) : N_NODES;
        int v3 = (j + 3 < deg) ? __shfl(cvec, gbase + 3, 64) : N_NODES;
        int v4 = (j + 4 < deg) ? __shfl(cvec, gbase + 4, 64) : N_NODES;
        int v5 = (j + 5 < deg) ? __shfl(cvec, gbase + 5, 64) : N_NODES;
        int v6 = (j + 6 < deg) ? __shfl(cvec, gbase + 6, 64) : N_NODES;
        int v7 = (j + 7 < deg) ? __shfl(cvec, gbase + 7, 64) : N_NODES;
        uint2 q0 = yin[(size_t)v0 * 8 + f];
        uint2 q1 = yin[(size_t)v1 * 8 + f];
        uint2 q2 = yin[(size_t)v2 * 8 + f];
        uint2 q3 = yin[(size_t)v3 * 8 + f];
        uint2 q4 = yin[(size_t)v4 * 8 + f];
        uint2 q5 = yin[(size_t)v5 * 8 + f];
        uint2 q6 = yin[(size_t)v6 * 8 + f];
        uint2 q7 = yin[(size_t)v7 * 8 + f];
        ACC8(q0) ACC8(q1) ACC8(q2) ACC8(q3)
        ACC8(q4) ACC8(q5) ACC8(q6) ACC8(q7)
        cvec = cnext;
    }
    #undef ACC8

    size_t orow = (size_t)node * (OUT_STRIDE / 4) + 2 * f;
    outcol4[orow]     = make_float4(di * a0, di * a1, di * a2, di * a3);
    outcol4[orow + 1] = make_float4(di * a4, di * a5, di * a6, di * a7);
    if (WRITE_HALF) {
        float di2 = di * di;
        uint2 w;
        w.x = pack_fp8x4(di2 * a0, di2 * a1, di2 * a2, di2 * a3);
        w.y = pack_fp8x4(di2 * a4, di2 * a5, di2 * a6, di2 * a7);
        yout[(size_t)node * 8 + f] = w;
        if (blockIdx.x == 0 && threadIdx.x < 8)
            yout[(size_t)N_NODES * 8 + threadIdx.x] = make_uint2(0u, 0u);  // zero row
    }
}

// ---------------- launch ----------------

extern "C" void kernel_launch(void* const* d_in, const int* in_sizes, int n_in,
                              void* d_out, int out_size, void* d_ws, size_t ws_size,
                              hipStream_t stream) {
    const float* feature = (const float*)d_in[0];
    const int* edge = (const int*)d_in[1];
    const int* src = edge;            // edge_index[0]
    const int* dst = edge + N_EDGES;  // edge_index[1]
    float* out = (float*)d_out;
    char* ws = (char*)d_ws;

    unsigned* p     = (unsigned*)(ws + OFF_P);
    int*      bases = (int*)(ws + OFF_BASES);
    int*      off   = (int*)(ws + OFF_OFF);
    int*      bsum  = (int*)(ws + OFF_BSUM);
    unsigned* totW  = (unsigned*)(ws + OFF_TOTW);
    float*    dinv  = (float*)(ws + OFF_DINV);
    int*      csr   = (int*)(ws + OFF_CSR);
    int*      dpart = (int*)(ws + OFF_DPART);
    int*      dbase = (int*)(ws + OFF_DBASE);
    int*      perm  = (int*)(ws + OFF_PERM);
    uint2*    xa    = (uint2*)(ws + OFF_XA);
    uint2*    xb    = (uint2*)(ws + OFF_XB);

    const int TB = 256;
    const int NB_NODES = (N_NODES + TB - 1) / TB;
    // ---- build normalization + CSR: zero global atomics, zero memsets
    k_hist<<<NPART, 256, 0, stream>>>(src, dst, p);
    k_sum<<<(NWORD + TB - 1) / TB, TB, 0, stream>>>(p, dinv, totW);
    k_x0<<<((N_NODES + 1) * 16 + TB - 1) / TB, TB, 0, stream>>>(
        (const float4*)feature, (float4*)out, (unsigned*)xb, dinv);
    k_scan_sums<<<SCAN_NB, 256, 0, stream>>>(totW, bsum);
    k_scan_top<<<1, 64, 0, stream>>>(bsum);
    k_scan_downA<<<SCAN_NB, 256, 0, stream>>>(totW, bsum, off);
    // ---- LPT degree sort (needs off only)
    k_dhist<<<DNB, 256, 0, stream>>>(off, dpart);
    k_dscan<<<1, 256, 0, stream>>>(dpart, dbase);
    k_dplace<<<DNB, 256, 0, stream>>>(off, dbase, perm);
    // ---- CSR scatter
    k_bases<<<NB_NODES, TB, 0, stream>>>(p, off, bases);
    k_scatter<<<NPART, 256, 0, stream>>>(src, dst, bases, csr);
    // ---- K hops, fp8 ping-pong y buffers (XB -> XA -> XB -> ...)
    const int hop_blocks = (NOCT * 64 + TB - 1) / TB;  // 1563
    for (int k = 1; k <= K_HOPS; ++k) {
        const uint2* yin = (k & 1) ? xb : xa;
        uint2* yout      = (k & 1) ? xa : xb;
        float4* outcol4 = (float4*)out + (size_t)k * 16;
        if (k < K_HOPS)
            k_hopf8<true><<<hop_blocks, TB, 0, stream>>>(yin, outcol4, yout, off, csr, dinv, perm);
        else
            k_hopf8<false><<<hop_blocks, TB, 0, stream>>>(yin, outcol4, nullptr, off, csr, dinv, perm);
    }
}